// Round 1
// baseline (503.360 us; speedup 1.0000x reference)
//
#include <hip/hip_runtime.h>
#include <hip/hip_bf16.h>

// GCN 7-layer forward on MI355X.
// Plan: build CSR (dst-sorted edge list) once per call, then per layer either
//   [GEMM(prescale) -> agg(post+bias+relu)]  (when din > dout)  or
//   [agg(prescale) -> GEMM(post+bias+relu)]  (otherwise)
// matching the reference's mult-first heuristic. All fp32.

#define IN_F 128

// ---------------- degree / norm / CSR build ----------------

__global__ void zero_int_kernel(int* p, int n) {
    int i = blockIdx.x * blockDim.x + threadIdx.x;
    if (i < n) p[i] = 0;
}

__global__ void deg_kernel(const int* __restrict__ src, const int* __restrict__ dst,
                           int* __restrict__ out_deg, int* __restrict__ in_deg, int E) {
    int e = blockIdx.x * blockDim.x + threadIdx.x;
    if (e < E) {
        atomicAdd(&out_deg[src[e]], 1);
        atomicAdd(&in_deg[dst[e]], 1);
    }
}

__global__ void norm_kernel(const int* __restrict__ out_deg, const int* __restrict__ in_deg,
                            float* __restrict__ out_nrm, float* __restrict__ in_nrm, int N) {
    int n = blockIdx.x * blockDim.x + threadIdx.x;
    if (n < N) {
        int d0 = out_deg[n];
        int d1 = in_deg[n];
        out_nrm[n] = d0 > 0 ? rsqrtf((float)d0) : 0.f;
        in_nrm[n]  = d1 > 0 ? rsqrtf((float)d1) : 0.f;
    }
}

// single-block exclusive scan of in_deg -> row_off[0..N], cursor copy
__global__ __launch_bounds__(1024) void scan_kernel(const int* __restrict__ in_deg,
                                                    int* __restrict__ row_off,
                                                    int* __restrict__ cursor, int N) {
    __shared__ int part[1024];
    const int t = threadIdx.x;
    const int CH = (N + 1023) / 1024;
    const int lo = t * CH;
    const int hi = min(lo + CH, N);
    int s = 0;
    for (int i = lo; i < hi; ++i) s += in_deg[i];
    part[t] = s;
    __syncthreads();
    for (int off = 1; off < 1024; off <<= 1) {
        int v = (t >= off) ? part[t - off] : 0;
        __syncthreads();
        part[t] += v;
        __syncthreads();
    }
    int run = (t == 0) ? 0 : part[t - 1];
    for (int i = lo; i < hi; ++i) {
        row_off[i] = run;
        cursor[i] = run;
        run += in_deg[i];
    }
    if (t == 1023) row_off[N] = run;  // == E
}

__global__ void fill_kernel(const int* __restrict__ src, const int* __restrict__ dst,
                            int* __restrict__ cursor, int* __restrict__ csr, int E) {
    int e = blockIdx.x * blockDim.x + threadIdx.x;
    if (e < E) {
        int pos = atomicAdd(&cursor[dst[e]], 1);
        csr[pos] = src[e];
    }
}

// ---------------- GEMM: Y[M,NOUT] = (X * pre?) @ W, epilogue (post+bias, relu)? ----------------
// 64x64 tile per 256-thread block, K chunked by 64, X-tile XOR-swizzled in LDS.

template<int K, int NOUT, bool PRE, bool POST, bool RELU>
__global__ __launch_bounds__(256) void gemm_kernel(
    const float* __restrict__ X, const float* __restrict__ W,
    const float* __restrict__ pre, const float* __restrict__ post,
    const float* __restrict__ bias, float* __restrict__ Y, int M) {
    constexpr int BK = 64;
    __shared__ float sX[64 * BK];  // [row][k] swizzled: k ^= (row&15)<<2
    __shared__ float sW[BK * 64];  // [k][col]
    const int tid = threadIdx.x;
    const int row0 = blockIdx.x * 64;
    const int col0 = blockIdx.y * 64;
    const int tc = tid & 15;
    const int tr = tid >> 4;
    const int rBase = tr * 4;
    const int cBase = tc * 4;

    float acc[4][4];
#pragma unroll
    for (int i = 0; i < 4; ++i)
#pragma unroll
        for (int j = 0; j < 4; ++j) acc[i][j] = 0.f;

    for (int kk = 0; kk < K; kk += BK) {
#pragma unroll
        for (int j = 0; j < 4; ++j) {
            int l = tid + 256 * j;        // float4 id
            int r = l >> 4;               // row 0..63
            int k4 = (l & 15) << 2;       // k offset
            float4 v = *reinterpret_cast<const float4*>(&X[(size_t)(row0 + r) * K + kk + k4]);
            if (PRE) {
                float s = pre[row0 + r];
                v.x *= s; v.y *= s; v.z *= s; v.w *= s;
            }
            int ks = k4 ^ ((r & 15) << 2);
            *reinterpret_cast<float4*>(&sX[r * BK + ks]) = v;
        }
#pragma unroll
        for (int j = 0; j < 4; ++j) {
            int l = tid + 256 * j;
            int k = l >> 4;
            int c4 = (l & 15) << 2;
            float4 v = *reinterpret_cast<const float4*>(&W[(size_t)(kk + k) * NOUT + col0 + c4]);
            *reinterpret_cast<float4*>(&sW[k * 64 + c4]) = v;
        }
        __syncthreads();
#pragma unroll
        for (int k = 0; k < BK; ++k) {
            float4 b = *reinterpret_cast<const float4*>(&sW[k * 64 + cBase]);
#pragma unroll
            for (int i = 0; i < 4; ++i) {
                int r = rBase + i;
                float a = sX[r * BK + (k ^ ((r & 15) << 2))];
                acc[i][0] += a * b.x;
                acc[i][1] += a * b.y;
                acc[i][2] += a * b.z;
                acc[i][3] += a * b.w;
            }
        }
        __syncthreads();
    }

#pragma unroll
    for (int i = 0; i < 4; ++i) {
        int r = row0 + rBase + i;
        float4 o = make_float4(acc[i][0], acc[i][1], acc[i][2], acc[i][3]);
        if (POST) {
            float pn = post[r];
            float4 b = *reinterpret_cast<const float4*>(&bias[col0 + cBase]);
            o.x = fmaf(o.x, pn, b.x);
            o.y = fmaf(o.y, pn, b.y);
            o.z = fmaf(o.z, pn, b.z);
            o.w = fmaf(o.w, pn, b.w);
        }
        if (RELU) {
            o.x = fmaxf(o.x, 0.f); o.y = fmaxf(o.y, 0.f);
            o.z = fmaxf(o.z, 0.f); o.w = fmaxf(o.w, 0.f);
        }
        *reinterpret_cast<float4*>(&Y[(size_t)r * NOUT + col0 + cBase]) = o;
    }
}

// ---------------- CSR aggregation: Y[n,:] = sum_{e: dst=n} X[src_e,:] * (pre[src_e]?) ----------------
// one wave per node, lane = feature (VPL features per lane)

template<int VPL, bool PRE, bool POST, bool RELU>
__global__ __launch_bounds__(256) void agg_kernel(
    const float* __restrict__ X, const int* __restrict__ csr,
    const int* __restrict__ row_off, const float* __restrict__ pre,
    const float* __restrict__ post, const float* __restrict__ bias,
    float* __restrict__ Y, int N) {
    const int lane = threadIdx.x & 63;
    const int node = blockIdx.x * (blockDim.x >> 6) + (threadIdx.x >> 6);
    if (node >= N) return;
    constexpr int F = VPL * 64;
    const int lo = row_off[node];
    const int hi = row_off[node + 1];
    float acc[VPL];
#pragma unroll
    for (int v = 0; v < VPL; ++v) acc[v] = 0.f;

    int e = lo;
    for (; e + 4 <= hi; e += 4) {
        int s0 = csr[e], s1 = csr[e + 1], s2 = csr[e + 2], s3 = csr[e + 3];
        float w0 = PRE ? pre[s0] : 1.f;
        float w1 = PRE ? pre[s1] : 1.f;
        float w2 = PRE ? pre[s2] : 1.f;
        float w3 = PRE ? pre[s3] : 1.f;
#pragma unroll
        for (int v = 0; v < VPL; ++v) {
            float x0 = X[(size_t)s0 * F + v * 64 + lane];
            float x1 = X[(size_t)s1 * F + v * 64 + lane];
            float x2 = X[(size_t)s2 * F + v * 64 + lane];
            float x3 = X[(size_t)s3 * F + v * 64 + lane];
            if (PRE)
                acc[v] += x0 * w0 + x1 * w1 + x2 * w2 + x3 * w3;
            else
                acc[v] += x0 + x1 + x2 + x3;
        }
    }
    for (; e < hi; ++e) {
        int s = csr[e];
        float w = PRE ? pre[s] : 1.f;
#pragma unroll
        for (int v = 0; v < VPL; ++v) {
            float x = X[(size_t)s * F + v * 64 + lane];
            acc[v] += PRE ? x * w : x;
        }
    }
    if (POST) {
        float pn = post[node];
#pragma unroll
        for (int v = 0; v < VPL; ++v) acc[v] = fmaf(acc[v], pn, bias[v * 64 + lane]);
    }
    if (RELU) {
#pragma unroll
        for (int v = 0; v < VPL; ++v) acc[v] = fmaxf(acc[v], 0.f);
    }
#pragma unroll
    for (int v = 0; v < VPL; ++v) Y[(size_t)node * F + v * 64 + lane] = acc[v];
}

// ---------------- layer 7 specials: GEMV (64 -> 1) and scalar aggregation ----------------

__global__ __launch_bounds__(256) void gemv64_kernel(const float* __restrict__ X,
                                                     const float* __restrict__ W,
                                                     const float* __restrict__ pre,
                                                     float* __restrict__ Y, int M) {
    const int lane = threadIdx.x & 63;
    const int m = blockIdx.x * (blockDim.x >> 6) + (threadIdx.x >> 6);
    if (m >= M) return;
    float v = X[(size_t)m * 64 + lane] * W[lane];
#pragma unroll
    for (int off = 32; off > 0; off >>= 1) v += __shfl_down(v, off);
    if (lane == 0) Y[m] = v * pre[m];
}

__global__ void agg1_kernel(const float* __restrict__ T, const int* __restrict__ csr,
                            const int* __restrict__ row_off, const float* __restrict__ post,
                            const float* __restrict__ bias, float* __restrict__ Y, int N) {
    int n = blockIdx.x * blockDim.x + threadIdx.x;
    if (n >= N) return;
    const int lo = row_off[n];
    const int hi = row_off[n + 1];
    float acc = 0.f;
    for (int e = lo; e < hi; ++e) acc += T[csr[e]];
    Y[n] = fmaf(acc, post[n], bias[0]);
}

// ---------------- host ----------------

extern "C" void kernel_launch(void* const* d_in, const int* in_sizes, int n_in,
                              void* d_out, int out_size, void* d_ws, size_t ws_size,
                              hipStream_t stream) {
    const float* in_feat = (const float*)d_in[0];
    const int* src = (const int*)d_in[1];
    const int* dst = (const int*)d_in[2];
    const float* W1 = (const float*)d_in[3];  const float* B1 = (const float*)d_in[4];
    const float* W2 = (const float*)d_in[5];  const float* B2 = (const float*)d_in[6];
    const float* W3 = (const float*)d_in[7];  const float* B3 = (const float*)d_in[8];
    const float* W4 = (const float*)d_in[9];  const float* B4 = (const float*)d_in[10];
    const float* W5 = (const float*)d_in[11]; const float* B5 = (const float*)d_in[12];
    const float* W6 = (const float*)d_in[13]; const float* B6 = (const float*)d_in[14];
    const float* W7 = (const float*)d_in[15]; const float* B7 = (const float*)d_in[16];

    const int N = in_sizes[0] / IN_F;   // 40000
    const int E = in_sizes[1];          // 640000
    float* out = (float*)d_out;

    // workspace layout (16B aligned chunks)
    char* w = (char*)d_ws;
    int* csr = (int*)w;        w += (size_t)E * 4;
    int* row_off = (int*)w;    w += (((size_t)(N + 1) * 4) + 15) / 16 * 16;
    int* cursor = (int*)w;     w += (size_t)N * 4;
    int* out_deg = (int*)w;    w += (size_t)N * 4;
    int* in_deg = (int*)w;     w += (size_t)N * 4;
    float* out_nrm = (float*)w; w += (size_t)N * 4;
    float* in_nrm = (float*)w;  w += (size_t)N * 4;
    float* b0 = (float*)w;     w += (size_t)N * 128 * 4;
    float* b1 = (float*)w;     w += (size_t)N * 128 * 4;
    float* b2 = (float*)w;     w += (size_t)N * 128 * 4;
    (void)ws_size; (void)n_in; (void)out_size;

    const int TB = 256;
    // CSR + norms
    zero_int_kernel<<<(2 * N + TB - 1) / TB, TB, 0, stream>>>(out_deg, 2 * N);
    deg_kernel<<<(E + TB - 1) / TB, TB, 0, stream>>>(src, dst, out_deg, in_deg, E);
    norm_kernel<<<(N + TB - 1) / TB, TB, 0, stream>>>(out_deg, in_deg, out_nrm, in_nrm, N);
    scan_kernel<<<1, 1024, 0, stream>>>(in_deg, row_off, cursor, N);
    fill_kernel<<<(E + TB - 1) / TB, TB, 0, stream>>>(src, dst, cursor, csr, E);

    const int gridN4 = (N + 3) / 4;   // wave-per-node kernels (4 waves/block)
    const int MB = N / 64;            // 625 row tiles

    // L1: 128->64, mult-first.  t1=b0 = (x*out_nrm)@W1 ; h1=b1 = relu(agg(t1)*in_nrm+b1)
    gemm_kernel<128, 64, true, false, false><<<dim3(MB, 1), TB, 0, stream>>>(
        in_feat, W1, out_nrm, nullptr, nullptr, b0, N);
    agg_kernel<1, false, true, true><<<gridN4, TB, 0, stream>>>(
        b0, csr, row_off, nullptr, in_nrm, B1, b1, N);

    // L2: 64->128, agg-first. t2=b0 = agg(h1*out_nrm) ; h2=b2 = relu(t2@W2*in_nrm+b2)
    agg_kernel<1, true, false, false><<<gridN4, TB, 0, stream>>>(
        b1, csr, row_off, out_nrm, nullptr, nullptr, b0, N);
    gemm_kernel<64, 128, false, true, true><<<dim3(MB, 2), TB, 0, stream>>>(
        b0, W2, nullptr, in_nrm, B2, b2, N);

    // L3: 128->128, agg-first. t3=b0 = agg(h2*out_nrm) ; h3=b1 = relu(t3@W3*in_nrm+b3)
    agg_kernel<2, true, false, false><<<gridN4, TB, 0, stream>>>(
        b2, csr, row_off, out_nrm, nullptr, nullptr, b0, N);
    gemm_kernel<128, 128, false, true, true><<<dim3(MB, 2), TB, 0, stream>>>(
        b0, W3, nullptr, in_nrm, B3, b1, N);

    // L4: 128->64, mult-first. t4=b0 = (h3*out_nrm)@W4 ; h4=b2 = relu(agg(t4)*in_nrm+b4)
    gemm_kernel<128, 64, true, false, false><<<dim3(MB, 1), TB, 0, stream>>>(
        b1, W4, out_nrm, nullptr, nullptr, b0, N);
    agg_kernel<1, false, true, true><<<gridN4, TB, 0, stream>>>(
        b0, csr, row_off, nullptr, in_nrm, B4, b2, N);

    // L5: 64->64, agg-first. t5=b0 = agg(h4*out_nrm) ; h5=b1 = relu(t5@W5*in_nrm+b5)
    agg_kernel<1, true, false, false><<<gridN4, TB, 0, stream>>>(
        b2, csr, row_off, out_nrm, nullptr, nullptr, b0, N);
    gemm_kernel<64, 64, false, true, true><<<dim3(MB, 1), TB, 0, stream>>>(
        b0, W5, nullptr, in_nrm, B5, b1, N);

    // L6: 64->64, agg-first. t6=b0 = agg(h5*out_nrm) ; h6=b2 = relu(t6@W6*in_nrm+b6)
    agg_kernel<1, true, false, false><<<gridN4, TB, 0, stream>>>(
        b1, csr, row_off, out_nrm, nullptr, nullptr, b0, N);
    gemm_kernel<64, 64, false, true, true><<<dim3(MB, 1), TB, 0, stream>>>(
        b0, W6, nullptr, in_nrm, B6, b2, N);

    // L7: 64->1, mult-first. t7=b0 = (h6*out_nrm)@W7 ; out = agg(t7)*in_nrm + b7
    gemv64_kernel<<<gridN4, TB, 0, stream>>>(b2, W7, out_nrm, b0, N);
    agg1_kernel<<<(N + TB - 1) / TB, TB, 0, stream>>>(b0, csr, row_off, in_nrm, B7, out, N);
}

// Round 2
// 408.397 us; speedup vs baseline: 1.2325x; 1.2325x over previous
//
#include <hip/hip_runtime.h>
#include <hip/hip_bf16.h>

// GCN 7-layer forward on MI355X. R2:
//  - multi-block scan (was 91us single-block)
//  - float4 gather aggregation (16B/lane), shfl_xor cross-edge reduce
//  - out_norm folded into producer epilogues (relu(x)*s == relu(x*s), s>=0)
// All fp32.

#define IN_F 128

// ---------------- degree / norm ----------------

__global__ void zero_int_kernel(int* p, int n) {
    int i = blockIdx.x * blockDim.x + threadIdx.x;
    if (i < n) p[i] = 0;
}

__global__ void deg_kernel(const int* __restrict__ src, const int* __restrict__ dst,
                           int* __restrict__ out_deg, int* __restrict__ in_deg, int E) {
    int e = blockIdx.x * blockDim.x + threadIdx.x;
    if (e < E) {
        atomicAdd(&out_deg[src[e]], 1);
        atomicAdd(&in_deg[dst[e]], 1);
    }
}

__global__ void norm_kernel(const int* __restrict__ out_deg, const int* __restrict__ in_deg,
                            float* __restrict__ out_nrm, float* __restrict__ in_nrm, int N) {
    int n = blockIdx.x * blockDim.x + threadIdx.x;
    if (n < N) {
        int d0 = out_deg[n];
        int d1 = in_deg[n];
        out_nrm[n] = d0 > 0 ? rsqrtf((float)d0) : 0.f;
        in_nrm[n]  = d1 > 0 ? rsqrtf((float)d1) : 0.f;
    }
}

// ---------------- multi-block exclusive scan of in_deg -> row_off[0..N] ----------------
// 1024 elements per 256-thread block (4/thread).

__global__ __launch_bounds__(256) void scan_blk_kernel(const int* __restrict__ deg,
                                                       int* __restrict__ blockSums, int N) {
    __shared__ int ws[4];
    const int t = threadIdx.x;
    const int base = blockIdx.x * 1024 + t * 4;
    int4 v = make_int4(0, 0, 0, 0);
    if (base + 3 < N) v = *reinterpret_cast<const int4*>(&deg[base]);
    else if (base < N) {
        v.x = deg[base];
        if (base + 1 < N) v.y = deg[base + 1];
        if (base + 2 < N) v.z = deg[base + 2];
    }
    int s = v.x + v.y + v.z + v.w;
#pragma unroll
    for (int off = 32; off > 0; off >>= 1) s += __shfl_down(s, off);
    if ((t & 63) == 0) ws[t >> 6] = s;
    __syncthreads();
    if (t == 0) blockSums[blockIdx.x] = ws[0] + ws[1] + ws[2] + ws[3];
}

// single wave scans <=64 block sums; writes exclusive block offsets and row_off[N]
__global__ __launch_bounds__(64) void scan_top_kernel(const int* __restrict__ blockSums,
                                                      int* __restrict__ blockOffs,
                                                      int* __restrict__ row_off, int NB, int N) {
    const int t = threadIdx.x;
    int orig = (t < NB) ? blockSums[t] : 0;
    int v = orig;
#pragma unroll
    for (int off = 1; off < 64; off <<= 1) {
        int u = __shfl_up(v, off);
        if (t >= off) v += u;
    }
    if (t < NB) blockOffs[t] = v - orig;
    if (t == 63) row_off[N] = v;  // total == E
}

__global__ __launch_bounds__(256) void scan_fill_kernel(const int* __restrict__ deg,
                                                        const int* __restrict__ blockOffs,
                                                        int* __restrict__ row_off,
                                                        int* __restrict__ cursor, int N) {
    __shared__ int wtot[4];
    const int t = threadIdx.x;
    const int lane = t & 63;
    const int wid = t >> 6;
    const int base = blockIdx.x * 1024 + t * 4;
    int4 v = make_int4(0, 0, 0, 0);
    if (base + 3 < N) v = *reinterpret_cast<const int4*>(&deg[base]);
    else if (base < N) {
        v.x = deg[base];
        if (base + 1 < N) v.y = deg[base + 1];
        if (base + 2 < N) v.z = deg[base + 2];
    }
    const int s = v.x + v.y + v.z + v.w;
    int incl = s;
#pragma unroll
    for (int off = 1; off < 64; off <<= 1) {
        int u = __shfl_up(incl, off);
        if (lane >= off) incl += u;
    }
    if (lane == 63) wtot[wid] = incl;
    __syncthreads();
    int pre = blockOffs[blockIdx.x] + incl - s;
    for (int i = 0; i < wid; ++i) pre += wtot[i];
    if (base < N) {
        int run = pre;
        row_off[base] = run; cursor[base] = run; run += v.x;
        if (base + 1 < N) { row_off[base + 1] = run; cursor[base + 1] = run; run += v.y; }
        if (base + 2 < N) { row_off[base + 2] = run; cursor[base + 2] = run; run += v.z; }
        if (base + 3 < N) { row_off[base + 3] = run; cursor[base + 3] = run; }
    }
}

__global__ void fill_kernel(const int* __restrict__ src, const int* __restrict__ dst,
                            int* __restrict__ cursor, int* __restrict__ csr, int E) {
    int e = blockIdx.x * blockDim.x + threadIdx.x;
    if (e < E) {
        int pos = atomicAdd(&cursor[dst[e]], 1);
        csr[pos] = src[e];
    }
}

// ---------------- GEMM: Y = (X * pre?) @ W, epilogue: (acc*r + bias)? relu? *s? ----------------

template<int K, int NOUT, bool PRE, bool POST, bool RELU, bool POST2>
__global__ __launch_bounds__(256) void gemm_kernel(
    const float* __restrict__ X, const float* __restrict__ W,
    const float* __restrict__ pre, const float* __restrict__ post,
    const float* __restrict__ post2, const float* __restrict__ bias,
    float* __restrict__ Y, int M) {
    constexpr int BK = 64;
    __shared__ float sX[64 * BK];  // [row][k] swizzled
    __shared__ float sW[BK * 64];  // [k][col]
    const int tid = threadIdx.x;
    const int row0 = blockIdx.x * 64;
    const int col0 = blockIdx.y * 64;
    const int tc = tid & 15;
    const int tr = tid >> 4;
    const int rBase = tr * 4;
    const int cBase = tc * 4;

    float acc[4][4];
#pragma unroll
    for (int i = 0; i < 4; ++i)
#pragma unroll
        for (int j = 0; j < 4; ++j) acc[i][j] = 0.f;

    for (int kk = 0; kk < K; kk += BK) {
#pragma unroll
        for (int j = 0; j < 4; ++j) {
            int l = tid + 256 * j;
            int r = l >> 4;
            int k4 = (l & 15) << 2;
            float4 v = *reinterpret_cast<const float4*>(&X[(size_t)(row0 + r) * K + kk + k4]);
            if (PRE) {
                float s = pre[row0 + r];
                v.x *= s; v.y *= s; v.z *= s; v.w *= s;
            }
            int ks = k4 ^ ((r & 15) << 2);
            *reinterpret_cast<float4*>(&sX[r * BK + ks]) = v;
        }
#pragma unroll
        for (int j = 0; j < 4; ++j) {
            int l = tid + 256 * j;
            int k = l >> 4;
            int c4 = (l & 15) << 2;
            float4 v = *reinterpret_cast<const float4*>(&W[(size_t)(kk + k) * NOUT + col0 + c4]);
            *reinterpret_cast<float4*>(&sW[k * 64 + c4]) = v;
        }
        __syncthreads();
#pragma unroll
        for (int k = 0; k < BK; ++k) {
            float4 b = *reinterpret_cast<const float4*>(&sW[k * 64 + cBase]);
#pragma unroll
            for (int i = 0; i < 4; ++i) {
                int r = rBase + i;
                float a = sX[r * BK + (k ^ ((r & 15) << 2))];
                acc[i][0] += a * b.x;
                acc[i][1] += a * b.y;
                acc[i][2] += a * b.z;
                acc[i][3] += a * b.w;
            }
        }
        __syncthreads();
    }

#pragma unroll
    for (int i = 0; i < 4; ++i) {
        int r = row0 + rBase + i;
        float4 o = make_float4(acc[i][0], acc[i][1], acc[i][2], acc[i][3]);
        if (POST) {
            float pn = post[r];
            float4 b = *reinterpret_cast<const float4*>(&bias[col0 + cBase]);
            o.x = fmaf(o.x, pn, b.x);
            o.y = fmaf(o.y, pn, b.y);
            o.z = fmaf(o.z, pn, b.z);
            o.w = fmaf(o.w, pn, b.w);
        }
        if (RELU) {
            o.x = fmaxf(o.x, 0.f); o.y = fmaxf(o.y, 0.f);
            o.z = fmaxf(o.z, 0.f); o.w = fmaxf(o.w, 0.f);
        }
        if (POST2) {
            float sn = post2[r];
            o.x *= sn; o.y *= sn; o.z *= sn; o.w *= sn;
        }
        *reinterpret_cast<float4*>(&Y[(size_t)r * NOUT + col0 + cBase]) = o;
    }
}

// ---------------- float4 CSR aggregation ----------------
// F=64: 16 lanes/row, 4 edges per wave-iter. F=128: 32 lanes/row, 2 edges.
// epilogue: (acc*r + bias)? relu? *s?

template<int F, bool POST, bool RELU, bool POST2>
__global__ __launch_bounds__(256) void agg4_kernel(
    const float* __restrict__ X, const int* __restrict__ csr,
    const int* __restrict__ row_off, const float* __restrict__ r_nrm,
    const float* __restrict__ s_nrm, const float* __restrict__ bias,
    float* __restrict__ Y, int N) {
    constexpr int LPE = F / 4;    // lanes per edge row
    constexpr int EPW = 64 / LPE; // edges in flight per wave iteration
    const int lane = threadIdx.x & 63;
    const int node = blockIdx.x * (blockDim.x >> 6) + (threadIdx.x >> 6);
    if (node >= N) return;
    const int g = lane / LPE;
    const int c = lane % LPE;
    const int lo = row_off[node];
    const int hi = row_off[node + 1];
    float4 acc = make_float4(0.f, 0.f, 0.f, 0.f);
    for (int e = lo + g; e < hi; e += EPW) {
        int s = csr[e];
        const float4 x = *reinterpret_cast<const float4*>(&X[(size_t)s * F + c * 4]);
        acc.x += x.x; acc.y += x.y; acc.z += x.z; acc.w += x.w;
    }
#pragma unroll
    for (int m = 32; m >= LPE; m >>= 1) {
        acc.x += __shfl_xor(acc.x, m);
        acc.y += __shfl_xor(acc.y, m);
        acc.z += __shfl_xor(acc.z, m);
        acc.w += __shfl_xor(acc.w, m);
    }
    if (lane < LPE) {
        float4 o = acc;
        if (POST) {
            float rn = r_nrm[node];
            const float4 b = *reinterpret_cast<const float4*>(&bias[c * 4]);
            o.x = fmaf(o.x, rn, b.x);
            o.y = fmaf(o.y, rn, b.y);
            o.z = fmaf(o.z, rn, b.z);
            o.w = fmaf(o.w, rn, b.w);
        }
        if (RELU) {
            o.x = fmaxf(o.x, 0.f); o.y = fmaxf(o.y, 0.f);
            o.z = fmaxf(o.z, 0.f); o.w = fmaxf(o.w, 0.f);
        }
        if (POST2) {
            float sn = s_nrm[node];
            o.x *= sn; o.y *= sn; o.z *= sn; o.w *= sn;
        }
        *reinterpret_cast<float4*>(&Y[(size_t)node * F + c * 4]) = o;
    }
}

// ---------------- layer 7: GEMV (64->1) and scalar aggregation ----------------

__global__ __launch_bounds__(256) void gemv64_kernel(const float* __restrict__ X,
                                                     const float* __restrict__ W,
                                                     float* __restrict__ Y, int M) {
    const int lane = threadIdx.x & 63;
    const int m = blockIdx.x * (blockDim.x >> 6) + (threadIdx.x >> 6);
    if (m >= M) return;
    float v = X[(size_t)m * 64 + lane] * W[lane];
#pragma unroll
    for (int off = 32; off > 0; off >>= 1) v += __shfl_down(v, off);
    if (lane == 0) Y[m] = v;
}

// 16-lane group per node (16 nodes / 256-thread block)
__global__ __launch_bounds__(256) void agg1_kernel(const float* __restrict__ T,
                                                   const int* __restrict__ csr,
                                                   const int* __restrict__ row_off,
                                                   const float* __restrict__ r_nrm,
                                                   const float* __restrict__ bias,
                                                   float* __restrict__ Y, int N) {
    const int node = blockIdx.x * 16 + (threadIdx.x >> 4);
    const int l = threadIdx.x & 15;
    if (node >= N) return;
    const int lo = row_off[node];
    const int hi = row_off[node + 1];
    float acc = 0.f;
    for (int e = lo + l; e < hi; e += 16) acc += T[csr[e]];
#pragma unroll
    for (int m = 8; m >= 1; m >>= 1) acc += __shfl_xor(acc, m);
    if (l == 0) Y[node] = fmaf(acc, r_nrm[node], bias[0]);
}

// ---------------- host ----------------

extern "C" void kernel_launch(void* const* d_in, const int* in_sizes, int n_in,
                              void* d_out, int out_size, void* d_ws, size_t ws_size,
                              hipStream_t stream) {
    const float* in_feat = (const float*)d_in[0];
    const int* src = (const int*)d_in[1];
    const int* dst = (const int*)d_in[2];
    const float* W1 = (const float*)d_in[3];  const float* B1 = (const float*)d_in[4];
    const float* W2 = (const float*)d_in[5];  const float* B2 = (const float*)d_in[6];
    const float* W3 = (const float*)d_in[7];  const float* B3 = (const float*)d_in[8];
    const float* W4 = (const float*)d_in[9];  const float* B4 = (const float*)d_in[10];
    const float* W5 = (const float*)d_in[11]; const float* B5 = (const float*)d_in[12];
    const float* W6 = (const float*)d_in[13]; const float* B6 = (const float*)d_in[14];
    const float* W7 = (const float*)d_in[15]; const float* B7 = (const float*)d_in[16];

    const int N = in_sizes[0] / IN_F;   // 40000
    const int E = in_sizes[1];          // 640000
    float* out = (float*)d_out;

    // workspace layout
    char* w = (char*)d_ws;
    int* csr = (int*)w;         w += (size_t)E * 4;
    int* row_off = (int*)w;     w += (((size_t)(N + 1) * 4) + 15) / 16 * 16;
    int* cursor = (int*)w;      w += (size_t)N * 4;
    int* out_deg = (int*)w;     w += (size_t)N * 4;
    int* in_deg = (int*)w;      w += (size_t)N * 4;
    int* blockSums = (int*)w;   w += 64 * 4;
    int* blockOffs = (int*)w;   w += 64 * 4;
    float* out_nrm = (float*)w; w += (size_t)N * 4;
    float* in_nrm = (float*)w;  w += (size_t)N * 4;
    float* b0 = (float*)w;      w += (size_t)N * 128 * 4;
    float* b1 = (float*)w;      w += (size_t)N * 128 * 4;
    float* b2 = (float*)w;      w += (size_t)N * 128 * 4;
    (void)ws_size; (void)n_in; (void)out_size;

    const int TB = 256;
    const int NB = (N + 1023) / 1024;  // scan blocks (40)

    // CSR + norms
    zero_int_kernel<<<(2 * N + TB - 1) / TB, TB, 0, stream>>>(out_deg, 2 * N);
    deg_kernel<<<(E + TB - 1) / TB, TB, 0, stream>>>(src, dst, out_deg, in_deg, E);
    norm_kernel<<<(N + TB - 1) / TB, TB, 0, stream>>>(out_deg, in_deg, out_nrm, in_nrm, N);
    scan_blk_kernel<<<NB, TB, 0, stream>>>(in_deg, blockSums, N);
    scan_top_kernel<<<1, 64, 0, stream>>>(blockSums, blockOffs, row_off, NB, N);
    scan_fill_kernel<<<NB, TB, 0, stream>>>(in_deg, blockOffs, row_off, cursor, N);
    fill_kernel<<<(E + TB - 1) / TB, TB, 0, stream>>>(src, dst, cursor, csr, E);

    const int gridN4 = (N + 3) / 4;   // 4 nodes per 256-thread block
    const int MB = N / 64;            // 625 row tiles

    // L1: 128->64 mult-first. b0 = (x*s)@W1 ; b1 = g1 = relu(agg(b0)*r+B1)*s
    gemm_kernel<128, 64, true, false, false, false><<<dim3(MB, 1), TB, 0, stream>>>(
        in_feat, W1, out_nrm, nullptr, nullptr, nullptr, b0, N);
    agg4_kernel<64, true, true, true><<<gridN4, TB, 0, stream>>>(
        b0, csr, row_off, in_nrm, out_nrm, B1, b1, N);

    // L2: 64->128 agg-first. b0 = agg(b1) ; b2 = g2 = relu(b0@W2*r+B2)*s
    agg4_kernel<64, false, false, false><<<gridN4, TB, 0, stream>>>(
        b1, csr, row_off, nullptr, nullptr, nullptr, b0, N);
    gemm_kernel<64, 128, false, true, true, true><<<dim3(MB, 2), TB, 0, stream>>>(
        b0, W2, nullptr, in_nrm, out_nrm, B2, b2, N);

    // L3: 128->128 agg-first. b0 = agg(b2) ; b1 = g3
    agg4_kernel<128, false, false, false><<<gridN4, TB, 0, stream>>>(
        b2, csr, row_off, nullptr, nullptr, nullptr, b0, N);
    gemm_kernel<128, 128, false, true, true, true><<<dim3(MB, 2), TB, 0, stream>>>(
        b0, W3, nullptr, in_nrm, out_nrm, B3, b1, N);

    // L4: 128->64 mult-first. b0 = b1@W4 (input pre-scaled) ; b2 = g4
    gemm_kernel<128, 64, false, false, false, false><<<dim3(MB, 1), TB, 0, stream>>>(
        b1, W4, nullptr, nullptr, nullptr, nullptr, b0, N);
    agg4_kernel<64, true, true, true><<<gridN4, TB, 0, stream>>>(
        b0, csr, row_off, in_nrm, out_nrm, B4, b2, N);

    // L5: 64->64 agg-first. b0 = agg(b2) ; b1 = g5
    agg4_kernel<64, false, false, false><<<gridN4, TB, 0, stream>>>(
        b2, csr, row_off, nullptr, nullptr, nullptr, b0, N);
    gemm_kernel<64, 64, false, true, true, true><<<dim3(MB, 1), TB, 0, stream>>>(
        b0, W5, nullptr, in_nrm, out_nrm, B5, b1, N);

    // L6: 64->64 agg-first. b0 = agg(b1) ; b2 = g6
    agg4_kernel<64, false, false, false><<<gridN4, TB, 0, stream>>>(
        b1, csr, row_off, nullptr, nullptr, nullptr, b0, N);
    gemm_kernel<64, 64, false, true, true, true><<<dim3(MB, 1), TB, 0, stream>>>(
        b0, W6, nullptr, in_nrm, out_nrm, B6, b2, N);

    // L7: 64->1 mult-first. b0 = b2@W7 (pre-scaled) ; out = agg(b0)*r + B7
    gemv64_kernel<<<gridN4, TB, 0, stream>>>(b2, W7, b0, N);
    agg1_kernel<<<(N + 15) / 16, TB, 0, stream>>>(b0, csr, row_off, in_nrm, B7, out, N);
}